// Round 7
// baseline (137.343 us; speedup 1.0000x reference)
//
#include <hip/hip_runtime.h>

#define KS 3
#define OUTC 3
#define FEATC 6
#define PATCH (FEATC * KS * KS)  // 54

#define BDIM 4
#define HDIM 512
#define WDIM 512
#define WQ (WDIM >> 2)            // 128
#define HW ((size_t)HDIM * WDIM)  // 262144

// persistent-grid config: 1024 blocks x 256 threads, 3 pixel-groups/thread
#define NBLOCKS 1024
#define ITERS 3                   // 1024*256*3 == 4*3*512*128 exactly

typedef float f32x4 __attribute__((ext_vector_type(4)));

// out[b,o,h,w] = sum_{c,dy,dx} feat[b,c,h+dy-1,w+dx-1] * km[b, o*54 + c*9 + dy*3 + dx, h, w]
//
// One thread: 4 consecutive pixels (w0..w0+3), one output channel o, repeated
// for 3 grid-strided pixel-groups.
// vs R6 (134.8us): grid 3072 -> 1024 persistent blocks. At ~4-5 resident
// blocks/CU, 3072 blocks = 2.4-3.0 scheduling rounds with a ragged ~50us
// partial-occupancy tail. 1024 blocks are all co-resident; every thread does
// exactly ITERS=3 groups -> zero tail. Outer loop unrolling disabled so
// register pressure stays at R6's level (no spill; R4/R5 lesson).
__global__ __launch_bounds__(256) void supersample_kernel(
    const float* __restrict__ feat,
    const float* __restrict__ km,
    float* __restrict__ out)
{
    const int tid = blockIdx.x * 256 + threadIdx.x;   // 0..262143

#pragma clang loop unroll(disable)
    for (int it = 0; it < ITERS; ++it) {
        const int idx = tid + it * (NBLOCKS * 256);

        const int wq = idx & (WQ - 1);
        int t = idx >> 7;                 // / WQ
        const int h = t & (HDIM - 1);
        t >>= 9;                          // / HDIM
        const int o = t % OUTC;
        const int b = t / OUTC;
        const int w0 = wq << 2;

        const float* featb = feat + (size_t)b * FEATC * HW;
        const float* kmo   = km   + ((size_t)b * OUTC + o) * PATCH * HW
                                   + (size_t)h * WDIM + w0;
        float*       outp  = out  + ((size_t)b * OUTC + o) * HW + (size_t)h * WDIM + w0;

        f32x4 acc = (f32x4)0.f;

#pragma unroll
        for (int c = 0; c < FEATC; ++c) {
            // 1) issue all 9 nt km loads for this (o,c) first — keep HBM queue full
            const float* kmc = kmo + (size_t)(c * KS * KS) * HW;
            f32x4 k4[9];
#pragma unroll
            for (int t9 = 0; t9 < 9; ++t9)
                k4[t9] = __builtin_nontemporal_load(
                    reinterpret_cast<const f32x4*>(kmc + (size_t)t9 * HW));

            // 2) feat window r[ky][j] = feat[c, h+ky-1, w0-1+j], zero-padded
            float r[3][6];
#pragma unroll
            for (int ky = 0; ky < 3; ++ky) {
                const int hy = h + ky - 1;
                if (hy < 0 || hy >= HDIM) {
#pragma unroll
                    for (int j = 0; j < 6; ++j) r[ky][j] = 0.f;
                } else {
                    const float* row = featb + (size_t)c * HW + (size_t)hy * WDIM;
                    const f32x4 mid = *reinterpret_cast<const f32x4*>(row + w0);
                    r[ky][1] = mid.x; r[ky][2] = mid.y; r[ky][3] = mid.z; r[ky][4] = mid.w;
                    r[ky][0] = (w0 > 0)        ? row[w0 - 1] : 0.f;
                    r[ky][5] = (w0 + 4 < WDIM) ? row[w0 + 4] : 0.f;
                }
            }

            // 3) FMAs
#pragma unroll
            for (int ky = 0; ky < 3; ++ky) {
#pragma unroll
                for (int kx = 0; kx < 3; ++kx) {
                    const f32x4 k = k4[ky * 3 + kx];
                    acc.x = fmaf(r[ky][kx + 0], k.x, acc.x);
                    acc.y = fmaf(r[ky][kx + 1], k.y, acc.y);
                    acc.z = fmaf(r[ky][kx + 2], k.z, acc.z);
                    acc.w = fmaf(r[ky][kx + 3], k.w, acc.w);
                }
            }
        }

        *reinterpret_cast<f32x4*>(outp) = acc;
    }
}

extern "C" void kernel_launch(void* const* d_in, const int* in_sizes, int n_in,
                              void* d_out, int out_size, void* d_ws, size_t ws_size,
                              hipStream_t stream) {
    const float* feat = (const float*)d_in[0];
    const float* km   = (const float*)d_in[1];
    float* out        = (float*)d_out;

    supersample_kernel<<<NBLOCKS, 256, 0, stream>>>(feat, km, out);
}